// Round 10
// baseline (397.347 us; speedup 1.0000x reference)
//
#include <hip/hip_runtime.h>
#include <hip/hip_bf16.h>
#include <cstdint>
#include <cstddef>

typedef _Float16 fp16;
typedef _Float16 f16x8_t __attribute__((ext_vector_type(8)));
typedef float    f32x4_t __attribute__((ext_vector_type(4)));

#define MFMA16(a,b,c) __builtin_amdgcn_mfma_f32_16x16x32_f16((a),(b),(c),0,0,0)

static __device__ __forceinline__ float h2f(fp16 v){ return (float)v; }
static __device__ __forceinline__ fp16  f2h(float v){ return (fp16)v; }

typedef __attribute__((address_space(1))) void gvoid_t;
typedef __attribute__((address_space(3))) void lvoid_t;
static __device__ __forceinline__ void gld16(const void* g, void* l) {
    __builtin_amdgcn_global_load_lds((const gvoid_t*)g, (lvoid_t*)l, 16, 0, 0);
}

// ---------------- fp32 -> fp16 all-weights convert (one launch) ----------------
__global__ __launch_bounds__(256) void k_convert_all(
    const float* __restrict__ wq, const float* __restrict__ wk,
    const float* __restrict__ wv, const float* __restrict__ wo_,
    const float* __restrict__ wg, const float* __restrict__ wu,
    const float* __restrict__ wdn,
    fp16* __restrict__ dqkv, fp16* __restrict__ dwo,
    fp16* __restrict__ dgu, fp16* __restrict__ dwd) {
    int bid = blockIdx.x;
    const float* src; fp16* dst; int base;
    if (bid < 4096) {
        int seg = bid >> 10;
        base = (bid & 1023) * 1024;
        if      (seg == 0) { src = wq;  dst = dqkv; }
        else if (seg == 1) { src = wk;  dst = dqkv + (1 << 20); }
        else if (seg == 2) { src = wv;  dst = dqkv + (2 << 20); }
        else               { src = wo_; dst = dwo; }
    } else {
        int t = bid - 4096;
        int seg = t / 2816;
        base = (t - seg * 2816) * 1024;
        if      (seg == 0) { src = wg;  dst = dgu; }
        else if (seg == 1) { src = wu;  dst = dgu + 2816*1024; }
        else               { src = wdn; dst = dwd; }
    }
    int i = base + threadIdx.x * 4;
    float4 v = *(const float4*)(src + i);
    fp16 o[4] = { f2h(v.x), f2h(v.y), f2h(v.z), f2h(v.w) };
    *(uint2*)(dst + i) = *(uint2*)o;
}

// ---------------- LayerNorm over 1024 cols -> fp16 ----------------
__global__ __launch_bounds__(256) void k_layernorm(const float* __restrict__ x,
                                                   const float* __restrict__ g,
                                                   const float* __restrict__ b,
                                                   fp16* __restrict__ out) {
    int row = blockIdx.x;
    int tid = threadIdx.x;
    float4 v = ((const float4*)(x + (size_t)row * 1024))[tid];
    float s = v.x + v.y + v.z + v.w;
    float q = v.x*v.x + v.y*v.y + v.z*v.z + v.w*v.w;
    #pragma unroll
    for (int d = 32; d >= 1; d >>= 1) {
        s += __shfl_xor(s, d);
        q += __shfl_xor(q, d);
    }
    __shared__ float rs[4], rq[4];
    if ((tid & 63) == 0) { rs[tid >> 6] = s; rq[tid >> 6] = q; }
    __syncthreads();
    s = rs[0] + rs[1] + rs[2] + rs[3];
    q = rq[0] + rq[1] + rq[2] + rq[3];
    float mu   = s * (1.f/1024.f);
    float var  = q * (1.f/1024.f) - mu*mu;
    float rstd = rsqrtf(var + 1e-5f);
    float4 gg = ((const float4*)g)[tid];
    float4 bb = ((const float4*)b)[tid];
    fp16 o[4];
    o[0] = f2h((v.x-mu)*rstd*gg.x + bb.x);
    o[1] = f2h((v.y-mu)*rstd*gg.y + bb.y);
    o[2] = f2h((v.z-mu)*rstd*gg.z + bb.z);
    o[3] = f2h((v.w-mu)*rstd*gg.w + bb.w);
    *(uint2*)(out + (size_t)row*1024 + tid*4) = *(uint2*)o;
}

// ---------------- RoPE in-place on fp16 (pair d, d+32 per thread) ----------------
__global__ __launch_bounds__(256) void k_rope(fp16* __restrict__ t, int ld, float scale) {
    int idx = blockIdx.x * 256 + threadIdx.x;   // total 2*2048*16*32
    int i   = idx & 31;
    int h   = (idx >> 5) & 15;
    int row = idx >> 9;                          // 0..4095
    int pos = row & 2047;
    float ang = (float)pos * powf(10000.f, -(float)i * (1.f/32.f));
    float sn, cs;
    sincosf(ang, &sn, &cs);
    fp16* p = t + (size_t)row * ld + h*64 + i;
    float x1 = h2f(p[0]);
    float x2 = h2f(p[32]);
    p[0]  = f2h((x1*cs - x2*sn) * scale);
    p[32] = f2h((x2*cs + x1*sn) * scale);
}

// ---------------- flash attention ----------------
__global__ __launch_bounds__(256) void k_attention(const fp16* __restrict__ Aq,
                                                   const fp16* __restrict__ Bk,
                                                   int ld,
                                                   const fp16* __restrict__ vt,
                                                   const int* __restrict__ mask,
                                                   fp16* __restrict__ mh) {
    int bh = blockIdx.y;
    int b = bh >> 4, h = bh & 15;
    int i0 = blockIdx.x * 64;
    int tid = threadIdx.x;
    int lane = tid & 63, w = tid >> 6;
    int l15 = lane & 15, lg = lane >> 4;

    int qrow = i0 + w*16 + l15;
    const fp16* ap = Aq + (size_t)(b*2048 + qrow)*ld + h*64;
    f16x8_t af0 = *(const f16x8_t*)(ap + lg*8);        // d 0..31 slice
    f16x8_t af1 = *(const f16x8_t*)(ap + 32 + lg*8);   // d 32..63 slice

    __shared__ fp16 Kt[64*72];
    __shared__ fp16 Vt[64*72];
    __shared__ float mf[64];

    float m_run = -1e30f, l_run = 0.f;
    f32x4_t oacc[4];
    #pragma unroll
    for (int d2 = 0; d2 < 4; ++d2) oacc[d2] = f32x4_t{0.f,0.f,0.f,0.f};

    int sr = tid >> 3, sc = (tid & 7) * 8;
    const fp16* kbase = Bk + (size_t)(b*2048)*ld + h*64;
    const fp16* vbase = vt + (size_t)bh * 64 * 2048;
    const int*  mbase = mask + b*2048;

    for (int kt = 0; kt < 32; ++kt) {
        int j0 = kt * 64;
        uint4 kv0 = *(const uint4*)(kbase + (size_t)(j0 + sr)*ld + sc);
        uint4 kv1 = *(const uint4*)(kbase + (size_t)(j0 + sr + 32)*ld + sc);
        uint4 vv0 = *(const uint4*)(vbase + (size_t)sr*2048 + j0 + sc);
        uint4 vv1 = *(const uint4*)(vbase + (size_t)(sr + 32)*2048 + j0 + sc);
        int mv = (tid < 64) ? mbase[j0 + tid] : 0;
        __syncthreads();                   // prior tile's reads complete
        *(uint4*)&Kt[sr*72 + sc]        = kv0;
        *(uint4*)&Kt[(sr + 32)*72 + sc] = kv1;
        *(uint4*)&Vt[sr*72 + sc]        = vv0;
        *(uint4*)&Vt[(sr + 32)*72 + sc] = vv1;
        if (tid < 64) mf[tid] = mv ? 0.f : -1e9f;
        __syncthreads();

        #pragma unroll
        for (int kk = 0; kk < 2; ++kk) {   // 32-key groups
            f32x4_t st[2];
            #pragma unroll
            for (int t2 = 0; t2 < 2; ++t2) {
                int kr = kk*32 + 8*((lane >> 2) & 3) + 4*t2 + (lane & 3);
                const fp16* krow = &Kt[kr*72 + lg*8];
                f16x8_t k0 = *(const f16x8_t*)(krow);
                f16x8_t k1 = *(const f16x8_t*)(krow + 32);
                f32x4_t z = f32x4_t{0.f,0.f,0.f,0.f};
                z = MFMA16(k0, af0, z);
                z = MFMA16(k1, af1, z);
                st[t2] = z;
            }
            float sv[8];
            float tmax = -1e30f;
            #pragma unroll
            for (int t2 = 0; t2 < 2; ++t2)
                #pragma unroll
                for (int r = 0; r < 4; ++r) {
                    float xv = st[t2][r] + mf[kk*32 + 8*lg + 4*t2 + r];
                    sv[t2*4+r] = xv;
                    tmax = fmaxf(tmax, xv);
                }
            tmax = fmaxf(tmax, __shfl_xor(tmax, 16));
            tmax = fmaxf(tmax, __shfl_xor(tmax, 32));
            float mn = fmaxf(m_run, tmax);
            float alpha = __expf(m_run - mn);
            float p[8], ps = 0.f;
            #pragma unroll
            for (int ii = 0; ii < 8; ++ii) { p[ii] = __expf(sv[ii] - mn); ps += p[ii]; }
            ps += __shfl_xor(ps, 16);
            ps += __shfl_xor(ps, 32);
            l_run = l_run * alpha + ps;
            m_run = mn;
            #pragma unroll
            for (int d2 = 0; d2 < 4; ++d2) {
                oacc[d2][0] *= alpha; oacc[d2][1] *= alpha;
                oacc[d2][2] *= alpha; oacc[d2][3] *= alpha;
            }
            f16x8_t pv;
            #pragma unroll
            for (int ii = 0; ii < 8; ++ii) pv[ii] = f2h(p[ii]);
            #pragma unroll
            for (int d2 = 0; d2 < 4; ++d2) {
                f16x8_t vf = *(const f16x8_t*)&Vt[(d2*16 + l15)*72 + kk*32 + lg*8];
                oacc[d2] = MFMA16(vf, pv, oacc[d2]);
            }
        }
    }
    float inv = 1.f / l_run;
    fp16* op = mh + (size_t)(b*2048 + qrow)*1024 + h*64;
    #pragma unroll
    for (int d2 = 0; d2 < 4; ++d2) {
        fp16 o4[4];
        #pragma unroll
        for (int r = 0; r < 4; ++r) o4[r] = f2h(oacc[d2][r] * inv);
        *(uint2*)(op + d2*16 + lg*4) = *(uint2*)o4;
    }
}

// ======== 256x256-tile GEMM, BK=32, 8 waves, ring-3 LDS, SINGLE barrier/K-step ====
// Schedule per step: vmcnt(4) [tile t landed] -> s_barrier -> stage(t+2) -> ds_read+MFMA.
// Race-free: reads of buf[(t-1)%3] complete before each wave's barrier-t arrival;
// stage(t+2) (same buffer) is issued only after ALL waves pass barrier t.
// epi 2: gate/up split: n<splitN -> outB=fp16(silu(acc+b1[n])); else outB2=fp16(acc+b2)
__global__ __launch_bounds__(512, 2) void k_gemm256(const fp16* __restrict__ A,
                                                    const fp16* __restrict__ W,
                                                    int N, int K, int nMtiles,
                                                    int splitN,
                                                    const float* __restrict__ b1,
                                                    const float* __restrict__ b2,
                                                    fp16* __restrict__ outB,
                                                    fp16* __restrict__ outB2) {
    __shared__ fp16 As[3][256*32];   // 3 x 16KB per operand = 96KB total
    __shared__ fp16 Bs[3][256*32];
    int tid  = threadIdx.x;
    int lane = tid & 63, wid = tid >> 6;
    int l15 = lane & 15, lg = lane >> 4;
    int wm = wid >> 2, wn = wid & 3;              // 2 x 4 waves, per-wave 128x64
    int cpx = gridDim.x >> 3;
    int logical = (blockIdx.x & 7) * cpx + (blockIdx.x >> 3);
    int m0 = (logical % nMtiles) * 256;
    int n0 = (logical / nMtiles) * 256;

    f32x4_t acc[8][4];
    #pragma unroll
    for (int i = 0; i < 8; ++i)
        #pragma unroll
        for (int j = 0; j < 4; ++j) acc[i][j] = f32x4_t{0.f,0.f,0.f,0.f};

    int arow = wid*32 + (lane >> 2);
    int acol = ((lane & 3) * 8) ^ ((lane & 32) ? 16 : 0);   // pre-swizzled source
    const fp16* gA = A + (size_t)(m0 + arow) * K + acol;
    const fp16* gB = W + (size_t)(n0 + arow) * K + acol;
    int lbase = wid * 1024;

    auto stage = [&](int s) {
        int buf = s % 3;
        int k0 = s << 5;
        gld16(gA + k0,                &As[buf][lbase]);
        gld16(gA + k0 + 16*(size_t)K, &As[buf][lbase + 512]);
        gld16(gB + k0,                &Bs[buf][lbase]);
        gld16(gB + k0 + 16*(size_t)K, &Bs[buf][lbase + 512]);
    };

    int nt = K >> 5;
    stage(0); stage(1);

    for (int t = 0; t < nt; ++t) {
        // wait ONLY for tile t (stage t+1 stays in flight)
        if (t + 1 < nt) { asm volatile("s_waitcnt vmcnt(4)" ::: "memory"); }
        else            { asm volatile("s_waitcnt vmcnt(0)" ::: "memory"); }
        __builtin_amdgcn_s_barrier();             // tile t staged chip-wide; prior reads done
        if (t + 2 < nt) stage(t + 2);             // refill (t-1)%3 buffer, safe post-barrier
        int cur = t % 3;
        f16x8_t av[8], bv[4];
        #pragma unroll
        for (int mi = 0; mi < 8; ++mi) {
            int ar = wm*128 + mi*16 + l15;
            av[mi] = *(const f16x8_t*)&As[cur][ar*32 + ((lg*8) ^ ((ar & 8) ? 16 : 0))];
        }
        #pragma unroll
        for (int ni = 0; ni < 4; ++ni) {
            int br = wn*64 + ni*16 + l15;
            bv[ni] = *(const f16x8_t*)&Bs[cur][br*32 + ((lg*8) ^ ((br & 8) ? 16 : 0))];
        }
        __builtin_amdgcn_s_setprio(1);
        #pragma unroll
        for (int mi = 0; mi < 8; ++mi)
            #pragma unroll
            for (int ni = 0; ni < 4; ++ni)
                acc[mi][ni] = MFMA16(av[mi], bv[ni], acc[mi][ni]);
        __builtin_amdgcn_s_setprio(0);
    }

    #pragma unroll
    for (int mi = 0; mi < 8; ++mi) {
        int mbase = m0 + wm*128 + mi*16 + lg*4;
        #pragma unroll
        for (int ni = 0; ni < 4; ++ni) {
            int n = n0 + wn*64 + ni*16 + l15;
            if (n < splitN) {
                float zb = b1[n];
                #pragma unroll
                for (int r = 0; r < 4; ++r) {
                    float z = acc[mi][ni][r] + zb;
                    outB[(size_t)(mbase + r) * splitN + n] = f2h(z / (1.f + __expf(-z)));
                }
            } else {
                float zb = b2[n - splitN];
                #pragma unroll
                for (int r = 0; r < 4; ++r)
                    outB2[(size_t)(mbase + r) * splitN + (n - splitN)] = f2h(acc[mi][ni][r] + zb);
            }
        }
    }
}

// ======== 128x128-tile GEMM, BK=32, 4 waves, ring-3 LDS, SINGLE barrier/K-step ====
// epi 0: QKV (N=3072): n<2048 -> outB row-major ld 3072; n>=2048 -> V^T into outB2
// epi 1: outF = resid + acc
// epi 3: outF = resid + acc + bias[n]
__global__ __launch_bounds__(256, 3) void k_gemm_bt(const fp16* __restrict__ A,
                                                    const fp16* __restrict__ W,
                                                    int N, int K, int nMtiles,
                                                    int epi,
                                                    const float* __restrict__ bias,
                                                    const float* __restrict__ resid,
                                                    fp16* __restrict__ outB,
                                                    fp16* __restrict__ outB2,
                                                    float* __restrict__ outF) {
    __shared__ fp16 Asb[3][128*32];   // 3 x 8KB per operand = 48KB total
    __shared__ fp16 Bsb[3][128*32];
    int tid = threadIdx.x;
    int lane = tid & 63, wid = tid >> 6;
    int l15 = lane & 15, lg = lane >> 4;
    int cpx = gridDim.x >> 3;
    int logical = (blockIdx.x & 7) * cpx + (blockIdx.x >> 3);
    int m0 = (logical % nMtiles) * 128;
    int n0 = (logical / nMtiles) * 128;
    int wm = wid >> 1, wn = wid & 1;
    f32x4_t acc[4][4];
    #pragma unroll
    for (int i = 0; i < 4; ++i)
        #pragma unroll
        for (int j = 0; j < 4; ++j) acc[i][j] = f32x4_t{0.f,0.f,0.f,0.f};

    int srow = wid*16 + (lane >> 2);
    int scol = (lane & 3) * 8;
    const fp16* ga = A + (size_t)(m0 + srow) * K + scol;
    const fp16* gb = W + (size_t)(n0 + srow) * K + scol;

    auto stage = [&](int s) {
        int buf = s % 3;
        int k0 = s << 5;
        fp16* lA = &Asb[buf][wid * 512];
        fp16* lB = &Bsb[buf][wid * 512];
        gld16(ga + k0,                lA);
        gld16(ga + (size_t)64*K + k0, lA + 2048);
        gld16(gb + k0,                lB);
        gld16(gb + (size_t)64*K + k0, lB + 2048);
    };

    int nt = K >> 5;
    stage(0); stage(1);

    for (int t = 0; t < nt; ++t) {
        if (t + 1 < nt) { asm volatile("s_waitcnt vmcnt(4)" ::: "memory"); }
        else            { asm volatile("s_waitcnt vmcnt(0)" ::: "memory"); }
        __builtin_amdgcn_s_barrier();
        if (t + 2 < nt) stage(t + 2);
        int cur = t % 3;
        f16x8_t av[4], bv[4];
        #pragma unroll
        for (int mi = 0; mi < 4; ++mi)
            av[mi] = *(const f16x8_t*)&Asb[cur][(wm*64 + mi*16 + l15)*32 + lg*8];
        #pragma unroll
        for (int ni = 0; ni < 4; ++ni)
            bv[ni] = *(const f16x8_t*)&Bsb[cur][(wn*64 + ni*16 + l15)*32 + lg*8];
        __builtin_amdgcn_s_setprio(1);
        #pragma unroll
        for (int mi = 0; mi < 4; ++mi)
            #pragma unroll
            for (int ni = 0; ni < 4; ++ni)
                acc[mi][ni] = MFMA16(av[mi], bv[ni], acc[mi][ni]);
        __builtin_amdgcn_s_setprio(0);
    }

    #pragma unroll
    for (int mi = 0; mi < 4; ++mi) {
        int mbase = m0 + wm*64 + mi*16 + lg*4;
        #pragma unroll
        for (int ni = 0; ni < 4; ++ni) {
            int n = n0 + wn*64 + ni*16 + l15;
            if (epi == 0) {
                if (n < 2048) {
                    #pragma unroll
                    for (int r = 0; r < 4; ++r)
                        outB[(size_t)(mbase + r) * 3072 + n] = f2h(acc[mi][ni][r]);
                } else {
                    int b = mbase >> 11;
                    int s = mbase & 2047;
                    int hd = n - 2048;
                    fp16 o4[4];
                    #pragma unroll
                    for (int r = 0; r < 4; ++r) o4[r] = f2h(acc[mi][ni][r]);
                    *(uint2*)(outB2 + (size_t)(b*1024 + hd) * 2048 + s) = *(uint2*)o4;
                }
            } else {
                #pragma unroll
                for (int r = 0; r < 4; ++r) {
                    int m = mbase + r;
                    float v = acc[mi][ni][r];
                    size_t idx = (size_t)m * N + n;
                    if (epi == 1) outF[idx] = resid[idx] + v;
                    else          outF[idx] = resid[idx] + v + bias[n];
                }
            }
        }
    }
}

// ---------------- elementwise gate multiply ----------------
__global__ __launch_bounds__(256) void k_mul(const fp16* __restrict__ a,
                                             const fp16* __restrict__ b,
                                             fp16* __restrict__ o, int n) {
    int i = (blockIdx.x * 256 + threadIdx.x) * 8;
    if (i >= n) return;
    uint4 va = *(const uint4*)(a + i);
    uint4 vb = *(const uint4*)(b + i);
    fp16* pa = (fp16*)&va; fp16* pb = (fp16*)&vb;
    fp16 ov[8];
    #pragma unroll
    for (int j = 0; j < 8; ++j) ov[j] = f2h(h2f(pa[j]) * h2f(pb[j]));
    *(uint4*)(o + i) = *(uint4*)ov;
}

extern "C" void kernel_launch(void* const* d_in, const int* in_sizes, int n_in,
                              void* d_out, int out_size, void* d_ws, size_t ws_size,
                              hipStream_t stream) {
    const float* x      = (const float*)d_in[0];
    const int*   mask   = (const int*)  d_in[1];
    const float* w_q    = (const float*)d_in[2];
    const float* w_k    = (const float*)d_in[3];
    const float* w_v    = (const float*)d_in[4];
    const float* w_o    = (const float*)d_in[5];
    const float* w_gate = (const float*)d_in[6];
    const float* b_gate = (const float*)d_in[7];
    const float* w_up   = (const float*)d_in[8];
    const float* b_up   = (const float*)d_in[9];
    const float* w_down = (const float*)d_in[10];
    const float* b_down = (const float*)d_in[11];
    const float* ln1g   = (const float*)d_in[12];
    const float* ln1b   = (const float*)d_in[13];
    const float* ln2g   = (const float*)d_in[14];
    const float* ln2b   = (const float*)d_in[15];
    float* out = (float*)d_out;

    char* ws = (char*)d_ws;
    size_t off = 0;
    auto walloc = [&](size_t bytes) -> void* {
        void* p = ws + off;
        off += (bytes + 255) & ~(size_t)255;
        return p;
    };
    fp16*  wqkv = (fp16*)walloc((size_t)3072*1024*2);
    fp16*  wo   = (fp16*)walloc((size_t)1024*1024*2);
    fp16*  wgu  = (fp16*)walloc((size_t)5632*1024*2);
    fp16*  wd   = (fp16*)walloc((size_t)1024*2816*2);
    fp16*  xn   = (fp16*)walloc((size_t)4096*1024*2);
    fp16*  qkv  = (fp16*)walloc((size_t)4096*3072*2);
    fp16*  vtb  = (fp16*)walloc((size_t)32*64*2048*2);
    fp16*  mh   = (fp16*)walloc((size_t)4096*1024*2);
    fp16*  sg   = (fp16*)walloc((size_t)4096*2816*2);
    fp16*  ub   = (fp16*)walloc((size_t)4096*2816*2);
    float* x1   = (float*)qkv;

    dim3 blk(256);
    k_convert_all<<<12544, blk, 0, stream>>>(w_q, w_k, w_v, w_o, w_gate, w_up, w_down,
                                             wqkv, wo, wgu, wd);

    // LN1
    k_layernorm<<<4096, blk, 0, stream>>>(x, ln1g, ln1b, xn);

    // QKV projection (N=3072), 128^2 ring-3 (768 blocks ~ 3/CU); V -> vtb transposed
    k_gemm_bt<<<768, blk, 0, stream>>>(xn, wqkv, 3072, 1024, 32, 0,
                                       nullptr, nullptr, qkv, vtb, nullptr);

    // rope: q_proj -> attention keys (scale 1), k_proj -> attention queries (1/8)
    k_rope<<<8192, blk, 0, stream>>>(qkv,        3072, 1.0f);
    k_rope<<<8192, blk, 0, stream>>>(qkv + 1024, 3072, 0.125f);

    // flash attention (reference q/k swap: A side = rope(k_proj))
    k_attention<<<dim3(32,32), blk, 0, stream>>>(qkv + 1024, qkv, 3072, vtb, mask, mh);

    // out projection + residual -> x1 (fp32)
    k_gemm_bt<<<256, blk, 0, stream>>>(mh, wo, 1024, 1024, 32, 1,
                                       nullptr, x, nullptr, nullptr, x1);

    // LN2
    k_layernorm<<<4096, blk, 0, stream>>>(x1, ln2g, ln2b, xn);

    // gate+up combined (N=5632), 256^2 ring-3, silu fused on gate half
    k_gemm256<<<352, 512, 0, stream>>>(xn, wgu, 5632, 1024, 16, 2816,
                                       b_gate, b_up, sg, ub);

    // h = silu(gate) * up
    k_mul<<<5632, blk, 0, stream>>>(sg, ub, sg, 4096*2816);

    // down projection + bias + residual -> out (fp32)
    k_gemm_bt<<<256, blk, 0, stream>>>(sg, wd, 1024, 2816, 32, 3,
                                       b_down, x1, nullptr, nullptr, out);
}

// Round 11
// 340.564 us; speedup vs baseline: 1.1667x; 1.1667x over previous
//
#include <hip/hip_runtime.h>
#include <hip/hip_bf16.h>
#include <cstdint>
#include <cstddef>

typedef _Float16 fp16;
typedef _Float16 f16x8_t __attribute__((ext_vector_type(8)));
typedef float    f32x4_t __attribute__((ext_vector_type(4)));

#define MFMA16(a,b,c) __builtin_amdgcn_mfma_f32_16x16x32_f16((a),(b),(c),0,0,0)

static __device__ __forceinline__ float h2f(fp16 v){ return (float)v; }
static __device__ __forceinline__ fp16  f2h(float v){ return (fp16)v; }

typedef __attribute__((address_space(1))) void gvoid_t;
typedef __attribute__((address_space(3))) void lvoid_t;
static __device__ __forceinline__ void gld16(const void* g, void* l) {
    __builtin_amdgcn_global_load_lds((const gvoid_t*)g, (lvoid_t*)l, 16, 0, 0);
}

// ---------------- fp32 -> fp16 all-weights convert (one launch) ----------------
__global__ __launch_bounds__(256) void k_convert_all(
    const float* __restrict__ wq, const float* __restrict__ wk,
    const float* __restrict__ wv, const float* __restrict__ wo_,
    const float* __restrict__ wg, const float* __restrict__ wu,
    const float* __restrict__ wdn,
    fp16* __restrict__ dqkv, fp16* __restrict__ dwo,
    fp16* __restrict__ dgu, fp16* __restrict__ dwd) {
    int bid = blockIdx.x;
    const float* src; fp16* dst; int base;
    if (bid < 4096) {
        int seg = bid >> 10;
        base = (bid & 1023) * 1024;
        if      (seg == 0) { src = wq;  dst = dqkv; }
        else if (seg == 1) { src = wk;  dst = dqkv + (1 << 20); }
        else if (seg == 2) { src = wv;  dst = dqkv + (2 << 20); }
        else               { src = wo_; dst = dwo; }
    } else {
        int t = bid - 4096;
        int seg = t / 2816;
        base = (t - seg * 2816) * 1024;
        if      (seg == 0) { src = wg;  dst = dgu; }
        else if (seg == 1) { src = wu;  dst = dgu + 2816*1024; }
        else               { src = wdn; dst = dwd; }
    }
    int i = base + threadIdx.x * 4;
    float4 v = *(const float4*)(src + i);
    fp16 o[4] = { f2h(v.x), f2h(v.y), f2h(v.z), f2h(v.w) };
    *(uint2*)(dst + i) = *(uint2*)o;
}

// ---------------- LayerNorm over 1024 cols -> fp16 ----------------
__global__ __launch_bounds__(256) void k_layernorm(const float* __restrict__ x,
                                                   const float* __restrict__ g,
                                                   const float* __restrict__ b,
                                                   fp16* __restrict__ out) {
    int row = blockIdx.x;
    int tid = threadIdx.x;
    float4 v = ((const float4*)(x + (size_t)row * 1024))[tid];
    float s = v.x + v.y + v.z + v.w;
    float q = v.x*v.x + v.y*v.y + v.z*v.z + v.w*v.w;
    #pragma unroll
    for (int d = 32; d >= 1; d >>= 1) {
        s += __shfl_xor(s, d);
        q += __shfl_xor(q, d);
    }
    __shared__ float rs[4], rq[4];
    if ((tid & 63) == 0) { rs[tid >> 6] = s; rq[tid >> 6] = q; }
    __syncthreads();
    s = rs[0] + rs[1] + rs[2] + rs[3];
    q = rq[0] + rq[1] + rq[2] + rq[3];
    float mu   = s * (1.f/1024.f);
    float var  = q * (1.f/1024.f) - mu*mu;
    float rstd = rsqrtf(var + 1e-5f);
    float4 gg = ((const float4*)g)[tid];
    float4 bb = ((const float4*)b)[tid];
    fp16 o[4];
    o[0] = f2h((v.x-mu)*rstd*gg.x + bb.x);
    o[1] = f2h((v.y-mu)*rstd*gg.y + bb.y);
    o[2] = f2h((v.z-mu)*rstd*gg.z + bb.z);
    o[3] = f2h((v.w-mu)*rstd*gg.w + bb.w);
    *(uint2*)(out + (size_t)row*1024 + tid*4) = *(uint2*)o;
}

// ---------------- flash attention ----------------
__global__ __launch_bounds__(256) void k_attention(const fp16* __restrict__ Aq,
                                                   const fp16* __restrict__ Bk,
                                                   int ld,
                                                   const fp16* __restrict__ vt,
                                                   const int* __restrict__ mask,
                                                   fp16* __restrict__ mh) {
    int bh = blockIdx.y;
    int b = bh >> 4, h = bh & 15;
    int i0 = blockIdx.x * 64;
    int tid = threadIdx.x;
    int lane = tid & 63, w = tid >> 6;
    int l15 = lane & 15, lg = lane >> 4;

    int qrow = i0 + w*16 + l15;
    const fp16* ap = Aq + (size_t)(b*2048 + qrow)*ld + h*64;
    f16x8_t af0 = *(const f16x8_t*)(ap + lg*8);        // d 0..31 slice
    f16x8_t af1 = *(const f16x8_t*)(ap + 32 + lg*8);   // d 32..63 slice

    __shared__ fp16 Kt[64*72];
    __shared__ fp16 Vt[64*72];
    __shared__ float mf[64];

    float m_run = -1e30f, l_run = 0.f;
    f32x4_t oacc[4];
    #pragma unroll
    for (int d2 = 0; d2 < 4; ++d2) oacc[d2] = f32x4_t{0.f,0.f,0.f,0.f};

    int sr = tid >> 3, sc = (tid & 7) * 8;
    const fp16* kbase = Bk + (size_t)(b*2048)*ld + h*64;
    const fp16* vbase = vt + (size_t)bh * 64 * 2048;
    const int*  mbase = mask + b*2048;

    for (int kt = 0; kt < 32; ++kt) {
        int j0 = kt * 64;
        uint4 kv0 = *(const uint4*)(kbase + (size_t)(j0 + sr)*ld + sc);
        uint4 kv1 = *(const uint4*)(kbase + (size_t)(j0 + sr + 32)*ld + sc);
        uint4 vv0 = *(const uint4*)(vbase + (size_t)sr*2048 + j0 + sc);
        uint4 vv1 = *(const uint4*)(vbase + (size_t)(sr + 32)*2048 + j0 + sc);
        int mv = (tid < 64) ? mbase[j0 + tid] : 0;
        __syncthreads();                   // prior tile's reads complete
        *(uint4*)&Kt[sr*72 + sc]        = kv0;
        *(uint4*)&Kt[(sr + 32)*72 + sc] = kv1;
        *(uint4*)&Vt[sr*72 + sc]        = vv0;
        *(uint4*)&Vt[(sr + 32)*72 + sc] = vv1;
        if (tid < 64) mf[tid] = mv ? 0.f : -1e9f;
        __syncthreads();

        #pragma unroll
        for (int kk = 0; kk < 2; ++kk) {   // 32-key groups
            f32x4_t st[2];
            #pragma unroll
            for (int t2 = 0; t2 < 2; ++t2) {
                int kr = kk*32 + 8*((lane >> 2) & 3) + 4*t2 + (lane & 3);
                const fp16* krow = &Kt[kr*72 + lg*8];
                f16x8_t k0 = *(const f16x8_t*)(krow);
                f16x8_t k1 = *(const f16x8_t*)(krow + 32);
                f32x4_t z = f32x4_t{0.f,0.f,0.f,0.f};
                z = MFMA16(k0, af0, z);
                z = MFMA16(k1, af1, z);
                st[t2] = z;
            }
            float sv[8];
            float tmax = -1e30f;
            #pragma unroll
            for (int t2 = 0; t2 < 2; ++t2)
                #pragma unroll
                for (int r = 0; r < 4; ++r) {
                    float xv = st[t2][r] + mf[kk*32 + 8*lg + 4*t2 + r];
                    sv[t2*4+r] = xv;
                    tmax = fmaxf(tmax, xv);
                }
            tmax = fmaxf(tmax, __shfl_xor(tmax, 16));
            tmax = fmaxf(tmax, __shfl_xor(tmax, 32));
            float mn = fmaxf(m_run, tmax);
            float alpha = __expf(m_run - mn);
            float p[8], ps = 0.f;
            #pragma unroll
            for (int ii = 0; ii < 8; ++ii) { p[ii] = __expf(sv[ii] - mn); ps += p[ii]; }
            ps += __shfl_xor(ps, 16);
            ps += __shfl_xor(ps, 32);
            l_run = l_run * alpha + ps;
            m_run = mn;
            #pragma unroll
            for (int d2 = 0; d2 < 4; ++d2) {
                oacc[d2][0] *= alpha; oacc[d2][1] *= alpha;
                oacc[d2][2] *= alpha; oacc[d2][3] *= alpha;
            }
            f16x8_t pv;
            #pragma unroll
            for (int ii = 0; ii < 8; ++ii) pv[ii] = f2h(p[ii]);
            #pragma unroll
            for (int d2 = 0; d2 < 4; ++d2) {
                f16x8_t vf = *(const f16x8_t*)&Vt[(d2*16 + l15)*72 + kk*32 + lg*8];
                oacc[d2] = MFMA16(vf, pv, oacc[d2]);
            }
        }
    }
    float inv = 1.f / l_run;
    fp16* op = mh + (size_t)(b*2048 + qrow)*1024 + h*64;
    #pragma unroll
    for (int d2 = 0; d2 < 4; ++d2) {
        fp16 o4[4];
        #pragma unroll
        for (int r = 0; r < 4; ++r) o4[r] = f2h(oacc[d2][r] * inv);
        *(uint2*)(op + d2*16 + lg*4) = *(uint2*)o4;
    }
}

// ======== 256x256-tile GEMM, BK=64, 8 waves, dbuf-2, r7 schedule ========
// Per K-step: stage(next) first -> ds_read+MFMA (kk loop) -> vmcnt(0) + barrier.
// Swizzle: read col ^= (row&7)<<3; staged global src col = 8*((lane&7)^((lane>>3)&7)).
// epi 2: gate/up split: n<splitN -> outB=fp16(silu(acc+b1[n])); else outB2=fp16(acc+b2)
__global__ __launch_bounds__(512, 2) void k_gemm256(const fp16* __restrict__ A,
                                                    const fp16* __restrict__ W,
                                                    int N, int K,
                                                    int splitN,
                                                    const float* __restrict__ b1,
                                                    const float* __restrict__ b2,
                                                    fp16* __restrict__ outB,
                                                    fp16* __restrict__ outB2) {
    __shared__ fp16 As[2][256*64];   // 32KB per buf per operand: 128KB total
    __shared__ fp16 Bs[2][256*64];
    int tid  = threadIdx.x;
    int lane = tid & 63, wid = tid >> 6;
    int l15 = lane & 15, lg = lane >> 4;
    int wm = wid >> 2, wn = wid & 3;              // 2 x 4 waves, per-wave 128x64
    int m0 = blockIdx.x * 256, n0 = blockIdx.y * 256;

    f32x4_t acc[8][4];
    #pragma unroll
    for (int i = 0; i < 8; ++i)
        #pragma unroll
        for (int j = 0; j < 4; ++j) acc[i][j] = f32x4_t{0.f,0.f,0.f,0.f};

    // staging: wave stages rows wid*32..+31 (4 chunks of 8 rows), pre-swizzled source
    int scol = 8 * ((lane & 7) ^ ((lane >> 3) & 7));
    const fp16* gA = A + (size_t)(m0 + wid*32 + (lane >> 3)) * K + scol;
    const fp16* gB = W + (size_t)(n0 + wid*32 + (lane >> 3)) * K + scol;
    int lbase = wid * 2048;                       // elements (32 rows x 64 cols)

    auto stage = [&](int buf, int k0) {
        #pragma unroll
        for (int j = 0; j < 4; ++j) {
            gld16(gA + k0 + (size_t)j*8*K, &As[buf][lbase + j*512]);
            gld16(gB + k0 + (size_t)j*8*K, &Bs[buf][lbase + j*512]);
        }
    };

    int nt = K >> 6;                              // BK = 64
    stage(0, 0);
    asm volatile("s_waitcnt vmcnt(0)" ::: "memory");
    __builtin_amdgcn_s_barrier();

    for (int t = 0; t < nt; ++t) {
        int cur = t & 1;
        if (t + 1 < nt) stage(cur ^ 1, (t + 1) << 6);   // issue next-tile loads first
        #pragma unroll
        for (int kk = 0; kk < 2; ++kk) {
            f16x8_t av[8], bv[4];
            #pragma unroll
            for (int mi = 0; mi < 8; ++mi) {
                int ar = wm*128 + mi*16 + l15;
                av[mi] = *(const f16x8_t*)&As[cur][ar*64 + ((kk*32 + lg*8) ^ ((ar & 7) << 3))];
            }
            #pragma unroll
            for (int ni = 0; ni < 4; ++ni) {
                int br = wn*64 + ni*16 + l15;
                bv[ni] = *(const f16x8_t*)&Bs[cur][br*64 + ((kk*32 + lg*8) ^ ((br & 7) << 3))];
            }
            __builtin_amdgcn_s_setprio(1);
            #pragma unroll
            for (int mi = 0; mi < 8; ++mi)
                #pragma unroll
                for (int ni = 0; ni < 4; ++ni)
                    acc[mi][ni] = MFMA16(av[mi], bv[ni], acc[mi][ni]);
            __builtin_amdgcn_s_setprio(0);
        }
        asm volatile("s_waitcnt vmcnt(0)" ::: "memory");
        __builtin_amdgcn_s_barrier();
    }

    #pragma unroll
    for (int mi = 0; mi < 8; ++mi) {
        int mbase = m0 + wm*128 + mi*16 + lg*4;
        #pragma unroll
        for (int ni = 0; ni < 4; ++ni) {
            int n = n0 + wn*64 + ni*16 + l15;
            if (n < splitN) {
                float zb = b1[n];
                #pragma unroll
                for (int r = 0; r < 4; ++r) {
                    float z = acc[mi][ni][r] + zb;
                    outB[(size_t)(mbase + r) * splitN + n] = f2h(z / (1.f + __expf(-z)));
                }
            } else {
                float zb = b2[n - splitN];
                #pragma unroll
                for (int r = 0; r < 4; ++r)
                    outB2[(size_t)(mbase + r) * splitN + (n - splitN)] = f2h(acc[mi][ni][r] + zb);
            }
        }
    }
}

// ======== 128x128-tile GEMM, BK=64, 4 waves, dbuf-2, r7 schedule, 2 blocks/CU ====
// epi 0: QKV (N=3072): n<2048 -> rope fused, row-major ld 3072; n>=2048 -> V^T to outB2
// epi 1: outF = resid + acc
// epi 3: outF = resid + acc + bias[n]
__global__ __launch_bounds__(256, 2) void k_gemm_bt(const fp16* __restrict__ A,
                                                    const fp16* __restrict__ W,
                                                    int N, int K,
                                                    int epi,
                                                    const float* __restrict__ bias,
                                                    const float* __restrict__ resid,
                                                    fp16* __restrict__ outB,
                                                    fp16* __restrict__ outB2,
                                                    float* __restrict__ outF) {
    __shared__ fp16 Asb[2][128*64];   // 16KB per buf per operand: 64KB total
    __shared__ fp16 Bsb[2][128*64];
    int tid = threadIdx.x;
    int lane = tid & 63, wid = tid >> 6;
    int l15 = lane & 15, lg = lane >> 4;
    int m0 = blockIdx.x * 128, n0 = blockIdx.y * 128;
    int wm = wid >> 1, wn = wid & 1;
    f32x4_t acc[4][4];
    #pragma unroll
    for (int i = 0; i < 4; ++i)
        #pragma unroll
        for (int j = 0; j < 4; ++j) acc[i][j] = f32x4_t{0.f,0.f,0.f,0.f};

    int scol = 8 * ((lane & 7) ^ ((lane >> 3) & 7));
    const fp16* ga = A + (size_t)(m0 + wid*32 + (lane >> 3)) * K + scol;
    const fp16* gb = W + (size_t)(n0 + wid*32 + (lane >> 3)) * K + scol;
    int lbase = wid * 2048;

    auto stage = [&](int buf, int k0) {
        #pragma unroll
        for (int j = 0; j < 4; ++j) {
            gld16(ga + k0 + (size_t)j*8*K, &Asb[buf][lbase + j*512]);
            gld16(gb + k0 + (size_t)j*8*K, &Bsb[buf][lbase + j*512]);
        }
    };

    int nt = K >> 6;
    stage(0, 0);
    asm volatile("s_waitcnt vmcnt(0)" ::: "memory");
    __builtin_amdgcn_s_barrier();

    for (int t = 0; t < nt; ++t) {
        int cur = t & 1;
        if (t + 1 < nt) stage(cur ^ 1, (t + 1) << 6);
        #pragma unroll
        for (int kk = 0; kk < 2; ++kk) {
            f16x8_t av[4], bv[4];
            #pragma unroll
            for (int mi = 0; mi < 4; ++mi) {
                int ar = wm*64 + mi*16 + l15;
                av[mi] = *(const f16x8_t*)&Asb[cur][ar*64 + ((kk*32 + lg*8) ^ ((ar & 7) << 3))];
            }
            #pragma unroll
            for (int ni = 0; ni < 4; ++ni) {
                int br = wn*64 + ni*16 + l15;
                bv[ni] = *(const f16x8_t*)&Bsb[cur][br*64 + ((kk*32 + lg*8) ^ ((br & 7) << 3))];
            }
            __builtin_amdgcn_s_setprio(1);
            #pragma unroll
            for (int mi = 0; mi < 4; ++mi)
                #pragma unroll
                for (int ni = 0; ni < 4; ++ni)
                    acc[mi][ni] = MFMA16(av[mi], bv[ni], acc[mi][ni]);
            __builtin_amdgcn_s_setprio(0);
        }
        asm volatile("s_waitcnt vmcnt(0)" ::: "memory");
        __builtin_amdgcn_s_barrier();
    }

    if (epi == 0) {
        if (n0 < 2048) {
            // q/k region: fused rope. lane holds both rotation halves (ni and ni+2).
            float scale = (n0 >= 1024) ? 0.125f : 1.0f;
            #pragma unroll
            for (int ni = 0; ni < 2; ++ni) {
                int i = ni*16 + l15;                       // freq index 0..31
                float theta = powf(10000.f, -(float)i * (1.f/32.f));
                int n = n0 + wn*64 + ni*16 + l15;
                #pragma unroll
                for (int mi = 0; mi < 4; ++mi) {
                    int mbase = m0 + wm*64 + mi*16 + lg*4;
                    #pragma unroll
                    for (int r = 0; r < 4; ++r) {
                        int m = mbase + r;
                        float ang = (float)(m & 2047) * theta;
                        float sn, cs;
                        sincosf(ang, &sn, &cs);
                        float x1 = acc[mi][ni][r];
                        float x2 = acc[mi][ni + 2][r];
                        outB[(size_t)m * 3072 + n]      = f2h((x1*cs - x2*sn) * scale);
                        outB[(size_t)m * 3072 + n + 32] = f2h((x2*cs + x1*sn) * scale);
                    }
                }
            }
        } else {
            // V region: write transposed (bh, 64, 2048)
            #pragma unroll
            for (int mi = 0; mi < 4; ++mi) {
                int mbase = m0 + wm*64 + mi*16 + lg*4;
                #pragma unroll
                for (int ni = 0; ni < 4; ++ni) {
                    int n = n0 + wn*64 + ni*16 + l15;
                    int b = mbase >> 11;
                    int s = mbase & 2047;
                    int hd = n - 2048;
                    fp16 o4[4];
                    #pragma unroll
                    for (int r = 0; r < 4; ++r) o4[r] = f2h(acc[mi][ni][r]);
                    *(uint2*)(outB2 + (size_t)(b*1024 + hd) * 2048 + s) = *(uint2*)o4;
                }
            }
        }
    } else {
        #pragma unroll
        for (int mi = 0; mi < 4; ++mi) {
            int mbase = m0 + wm*64 + mi*16 + lg*4;
            #pragma unroll
            for (int ni = 0; ni < 4; ++ni) {
                int n = n0 + wn*64 + ni*16 + l15;
                #pragma unroll
                for (int r = 0; r < 4; ++r) {
                    int m = mbase + r;
                    float v = acc[mi][ni][r];
                    size_t idx = (size_t)m * N + n;
                    if (epi == 1) outF[idx] = resid[idx] + v;
                    else          outF[idx] = resid[idx] + v + bias[n];
                }
            }
        }
    }
}

// ---------------- elementwise gate multiply ----------------
__global__ __launch_bounds__(256) void k_mul(const fp16* __restrict__ a,
                                             const fp16* __restrict__ b,
                                             fp16* __restrict__ o, int n) {
    int i = (blockIdx.x * 256 + threadIdx.x) * 8;
    if (i >= n) return;
    uint4 va = *(const uint4*)(a + i);
    uint4 vb = *(const uint4*)(b + i);
    fp16* pa = (fp16*)&va; fp16* pb = (fp16*)&vb;
    fp16 ov[8];
    #pragma unroll
    for (int j = 0; j < 8; ++j) ov[j] = f2h(h2f(pa[j]) * h2f(pb[j]));
    *(uint4*)(o + i) = *(uint4*)ov;
}

extern "C" void kernel_launch(void* const* d_in, const int* in_sizes, int n_in,
                              void* d_out, int out_size, void* d_ws, size_t ws_size,
                              hipStream_t stream) {
    const float* x      = (const float*)d_in[0];
    const int*   mask   = (const int*)  d_in[1];
    const float* w_q    = (const float*)d_in[2];
    const float* w_k    = (const float*)d_in[3];
    const float* w_v    = (const float*)d_in[4];
    const float* w_o    = (const float*)d_in[5];
    const float* w_gate = (const float*)d_in[6];
    const float* b_gate = (const float*)d_in[7];
    const float* w_up   = (const float*)d_in[8];
    const float* b_up   = (const float*)d_in[9];
    const float* w_down = (const float*)d_in[10];
    const float* b_down = (const float*)d_in[11];
    const float* ln1g   = (const float*)d_in[12];
    const float* ln1b   = (const float*)d_in[13];
    const float* ln2g   = (const float*)d_in[14];
    const float* ln2b   = (const float*)d_in[15];
    float* out = (float*)d_out;

    char* ws = (char*)d_ws;
    size_t off = 0;
    auto walloc = [&](size_t bytes) -> void* {
        void* p = ws + off;
        off += (bytes + 255) & ~(size_t)255;
        return p;
    };
    fp16*  wqkv = (fp16*)walloc((size_t)3072*1024*2);
    fp16*  wo   = (fp16*)walloc((size_t)1024*1024*2);
    fp16*  wgu  = (fp16*)walloc((size_t)5632*1024*2);
    fp16*  wd   = (fp16*)walloc((size_t)1024*2816*2);
    fp16*  xn   = (fp16*)walloc((size_t)4096*1024*2);
    fp16*  qkv  = (fp16*)walloc((size_t)4096*3072*2);
    fp16*  vtb  = (fp16*)walloc((size_t)32*64*2048*2);
    fp16*  mh   = (fp16*)walloc((size_t)4096*1024*2);
    fp16*  sg   = (fp16*)walloc((size_t)4096*2816*2);
    fp16*  ub   = (fp16*)walloc((size_t)4096*2816*2);
    float* x1   = (float*)qkv;

    dim3 blk(256);
    k_convert_all<<<12544, blk, 0, stream>>>(w_q, w_k, w_v, w_o, w_gate, w_up, w_down,
                                             wqkv, wo, wgu, wd);

    // LN1
    k_layernorm<<<4096, blk, 0, stream>>>(x, ln1g, ln1b, xn);

    // QKV projection (N=3072) with fused rope + V-transpose epilogue
    k_gemm_bt<<<dim3(32,24), blk, 0, stream>>>(xn, wqkv, 3072, 1024, 0,
                                               nullptr, nullptr, qkv, vtb, nullptr);

    // flash attention (reference q/k swap: A side = rope(k_proj)*0.125 at qkv+1024)
    k_attention<<<dim3(32,32), blk, 0, stream>>>(qkv + 1024, qkv, 3072, vtb, mask, mh);

    // out projection + residual -> x1 (fp32)
    k_gemm_bt<<<dim3(32,8), blk, 0, stream>>>(mh, wo, 1024, 1024, 1,
                                              nullptr, x, nullptr, nullptr, x1);

    // LN2
    k_layernorm<<<4096, blk, 0, stream>>>(x1, ln2g, ln2b, xn);

    // gate+up combined (N=5632), 256^2 BK=64, silu fused on gate half
    k_gemm256<<<dim3(16,22), 512, 0, stream>>>(xn, wgu, 5632, 1024, 2816,
                                               b_gate, b_up, sg, ub);

    // h = silu(gate) * up
    k_mul<<<5632, blk, 0, stream>>>(sg, ub, sg, 4096*2816);

    // down projection + bias + residual -> out (fp32)
    k_gemm_bt<<<dim3(32,8), blk, 0, stream>>>(sg, wd, 1024, 2816, 3,
                                              b_down, x1, nullptr, nullptr, out);
}

// Round 12
// 319.795 us; speedup vs baseline: 1.2425x; 1.0649x over previous
//
#include <hip/hip_runtime.h>
#include <hip/hip_bf16.h>
#include <cstdint>
#include <cstddef>

typedef _Float16 fp16;
typedef _Float16 f16x8_t __attribute__((ext_vector_type(8)));
typedef float    f32x4_t __attribute__((ext_vector_type(4)));

#define MFMA16(a,b,c) __builtin_amdgcn_mfma_f32_16x16x32_f16((a),(b),(c),0,0,0)

static __device__ __forceinline__ float h2f(fp16 v){ return (float)v; }
static __device__ __forceinline__ fp16  f2h(float v){ return (fp16)v; }

typedef __attribute__((address_space(1))) void gvoid_t;
typedef __attribute__((address_space(3))) void lvoid_t;
static __device__ __forceinline__ void gld16(const void* g, void* l) {
    __builtin_amdgcn_global_load_lds((const gvoid_t*)g, (lvoid_t*)l, 16, 0, 0);
}

// ---------------- fp32 -> fp16 all-weights convert (one launch) ----------------
__global__ __launch_bounds__(256) void k_convert_all(
    const float* __restrict__ wq, const float* __restrict__ wk,
    const float* __restrict__ wv, const float* __restrict__ wo_,
    const float* __restrict__ wg, const float* __restrict__ wu,
    const float* __restrict__ wdn,
    fp16* __restrict__ dqkv, fp16* __restrict__ dwo,
    fp16* __restrict__ dgu, fp16* __restrict__ dwd) {
    int bid = blockIdx.x;
    const float* src; fp16* dst; int base;
    if (bid < 4096) {
        int seg = bid >> 10;
        base = (bid & 1023) * 1024;
        if      (seg == 0) { src = wq;  dst = dqkv; }
        else if (seg == 1) { src = wk;  dst = dqkv + (1 << 20); }
        else if (seg == 2) { src = wv;  dst = dqkv + (2 << 20); }
        else               { src = wo_; dst = dwo; }
    } else {
        int t = bid - 4096;
        int seg = t / 2816;
        base = (t - seg * 2816) * 1024;
        if      (seg == 0) { src = wg;  dst = dgu; }
        else if (seg == 1) { src = wu;  dst = dgu + 2816*1024; }
        else               { src = wdn; dst = dwd; }
    }
    int i = base + threadIdx.x * 4;
    float4 v = *(const float4*)(src + i);
    fp16 o[4] = { f2h(v.x), f2h(v.y), f2h(v.z), f2h(v.w) };
    *(uint2*)(dst + i) = *(uint2*)o;
}

// ---------------- LayerNorm over 1024 cols -> fp16 ----------------
__global__ __launch_bounds__(256) void k_layernorm(const float* __restrict__ x,
                                                   const float* __restrict__ g,
                                                   const float* __restrict__ b,
                                                   fp16* __restrict__ out) {
    int row = blockIdx.x;
    int tid = threadIdx.x;
    float4 v = ((const float4*)(x + (size_t)row * 1024))[tid];
    float s = v.x + v.y + v.z + v.w;
    float q = v.x*v.x + v.y*v.y + v.z*v.z + v.w*v.w;
    #pragma unroll
    for (int d = 32; d >= 1; d >>= 1) {
        s += __shfl_xor(s, d);
        q += __shfl_xor(q, d);
    }
    __shared__ float rs[4], rq[4];
    if ((tid & 63) == 0) { rs[tid >> 6] = s; rq[tid >> 6] = q; }
    __syncthreads();
    s = rs[0] + rs[1] + rs[2] + rs[3];
    q = rq[0] + rq[1] + rq[2] + rq[3];
    float mu   = s * (1.f/1024.f);
    float var  = q * (1.f/1024.f) - mu*mu;
    float rstd = rsqrtf(var + 1e-5f);
    float4 gg = ((const float4*)g)[tid];
    float4 bb = ((const float4*)b)[tid];
    fp16 o[4];
    o[0] = f2h((v.x-mu)*rstd*gg.x + bb.x);
    o[1] = f2h((v.y-mu)*rstd*gg.y + bb.y);
    o[2] = f2h((v.z-mu)*rstd*gg.z + bb.z);
    o[3] = f2h((v.w-mu)*rstd*gg.w + bb.w);
    *(uint2*)(out + (size_t)row*1024 + tid*4) = *(uint2*)o;
}

// ---------------- flash attention ----------------
__global__ __launch_bounds__(256) void k_attention(const fp16* __restrict__ Aq,
                                                   const fp16* __restrict__ Bk,
                                                   int ld,
                                                   const fp16* __restrict__ vt,
                                                   const int* __restrict__ mask,
                                                   fp16* __restrict__ mh) {
    int bh = blockIdx.y;
    int b = bh >> 4, h = bh & 15;
    int i0 = blockIdx.x * 64;
    int tid = threadIdx.x;
    int lane = tid & 63, w = tid >> 6;
    int l15 = lane & 15, lg = lane >> 4;

    int qrow = i0 + w*16 + l15;
    const fp16* ap = Aq + (size_t)(b*2048 + qrow)*ld + h*64;
    f16x8_t af0 = *(const f16x8_t*)(ap + lg*8);        // d 0..31 slice
    f16x8_t af1 = *(const f16x8_t*)(ap + 32 + lg*8);   // d 32..63 slice

    __shared__ fp16 Kt[64*72];
    __shared__ fp16 Vt[64*72];
    __shared__ float mf[64];

    float m_run = -1e30f, l_run = 0.f;
    f32x4_t oacc[4];
    #pragma unroll
    for (int d2 = 0; d2 < 4; ++d2) oacc[d2] = f32x4_t{0.f,0.f,0.f,0.f};

    int sr = tid >> 3, sc = (tid & 7) * 8;
    const fp16* kbase = Bk + (size_t)(b*2048)*ld + h*64;
    const fp16* vbase = vt + (size_t)bh * 64 * 2048;
    const int*  mbase = mask + b*2048;

    for (int kt = 0; kt < 32; ++kt) {
        int j0 = kt * 64;
        uint4 kv0 = *(const uint4*)(kbase + (size_t)(j0 + sr)*ld + sc);
        uint4 kv1 = *(const uint4*)(kbase + (size_t)(j0 + sr + 32)*ld + sc);
        uint4 vv0 = *(const uint4*)(vbase + (size_t)sr*2048 + j0 + sc);
        uint4 vv1 = *(const uint4*)(vbase + (size_t)(sr + 32)*2048 + j0 + sc);
        int mv = (tid < 64) ? mbase[j0 + tid] : 0;
        __syncthreads();                   // prior tile's reads complete
        *(uint4*)&Kt[sr*72 + sc]        = kv0;
        *(uint4*)&Kt[(sr + 32)*72 + sc] = kv1;
        *(uint4*)&Vt[sr*72 + sc]        = vv0;
        *(uint4*)&Vt[(sr + 32)*72 + sc] = vv1;
        if (tid < 64) mf[tid] = mv ? 0.f : -1e9f;
        __syncthreads();

        #pragma unroll
        for (int kk = 0; kk < 2; ++kk) {   // 32-key groups
            f32x4_t st[2];
            __builtin_amdgcn_s_setprio(1);
            #pragma unroll
            for (int t2 = 0; t2 < 2; ++t2) {
                int kr = kk*32 + 8*((lane >> 2) & 3) + 4*t2 + (lane & 3);
                const fp16* krow = &Kt[kr*72 + lg*8];
                f16x8_t k0 = *(const f16x8_t*)(krow);
                f16x8_t k1 = *(const f16x8_t*)(krow + 32);
                f32x4_t z = f32x4_t{0.f,0.f,0.f,0.f};
                z = MFMA16(k0, af0, z);
                z = MFMA16(k1, af1, z);
                st[t2] = z;
            }
            __builtin_amdgcn_s_setprio(0);
            float sv[8];
            float tmax = -1e30f;
            #pragma unroll
            for (int t2 = 0; t2 < 2; ++t2)
                #pragma unroll
                for (int r = 0; r < 4; ++r) {
                    float xv = st[t2][r] + mf[kk*32 + 8*lg + 4*t2 + r];
                    sv[t2*4+r] = xv;
                    tmax = fmaxf(tmax, xv);
                }
            tmax = fmaxf(tmax, __shfl_xor(tmax, 16));
            tmax = fmaxf(tmax, __shfl_xor(tmax, 32));
            // exact defer-max: if no lane sees a new max, alpha == 1 identically
            bool newmax = !__all(tmax <= m_run);
            float mn = m_run;
            if (newmax) {
                mn = fmaxf(m_run, tmax);
                float alpha = __expf(m_run - mn);
                l_run *= alpha;
                #pragma unroll
                for (int d2 = 0; d2 < 4; ++d2) {
                    oacc[d2][0] *= alpha; oacc[d2][1] *= alpha;
                    oacc[d2][2] *= alpha; oacc[d2][3] *= alpha;
                }
                m_run = mn;
            }
            float p[8], ps = 0.f;
            #pragma unroll
            for (int ii = 0; ii < 8; ++ii) { p[ii] = __expf(sv[ii] - mn); ps += p[ii]; }
            ps += __shfl_xor(ps, 16);
            ps += __shfl_xor(ps, 32);
            l_run += ps;
            f16x8_t pv;
            #pragma unroll
            for (int ii = 0; ii < 8; ++ii) pv[ii] = f2h(p[ii]);
            __builtin_amdgcn_s_setprio(1);
            #pragma unroll
            for (int d2 = 0; d2 < 4; ++d2) {
                f16x8_t vf = *(const f16x8_t*)&Vt[(d2*16 + l15)*72 + kk*32 + lg*8];
                oacc[d2] = MFMA16(vf, pv, oacc[d2]);
            }
            __builtin_amdgcn_s_setprio(0);
        }
    }
    float inv = 1.f / l_run;
    fp16* op = mh + (size_t)(b*2048 + qrow)*1024 + h*64;
    #pragma unroll
    for (int d2 = 0; d2 < 4; ++d2) {
        fp16 o4[4];
        #pragma unroll
        for (int r = 0; r < 4; ++r) o4[r] = f2h(oacc[d2][r] * inv);
        *(uint2*)(op + d2*16 + lg*4) = *(uint2*)o4;
    }
}

// ======== 128x128-tile GEMM, BK=64, 4 waves, dbuf-2, r7 schedule, 2 blocks/CU ====
// epi 0: QKV (N=3072): n<2048 -> rope fused, row-major ld 3072; n>=2048 -> V^T to outB2
// epi 1: outF = resid + acc
// epi 2: gate/up split (N=5632): n<2816 -> outB=silu(acc+bias[n]); else outB2=acc+bias2
// epi 3: outF = resid + acc + bias[n]
__global__ __launch_bounds__(256, 2) void k_gemm_bt(const fp16* __restrict__ A,
                                                    const fp16* __restrict__ W,
                                                    int N, int K,
                                                    int epi,
                                                    const float* __restrict__ bias,
                                                    const float* __restrict__ bias2,
                                                    const float* __restrict__ resid,
                                                    fp16* __restrict__ outB,
                                                    fp16* __restrict__ outB2,
                                                    float* __restrict__ outF) {
    __shared__ fp16 Asb[2][128*64];   // 16KB per buf per operand: 64KB total
    __shared__ fp16 Bsb[2][128*64];
    int tid = threadIdx.x;
    int lane = tid & 63, wid = tid >> 6;
    int l15 = lane & 15, lg = lane >> 4;
    int m0 = blockIdx.x * 128, n0 = blockIdx.y * 128;
    int wm = wid >> 1, wn = wid & 1;
    f32x4_t acc[4][4];
    #pragma unroll
    for (int i = 0; i < 4; ++i)
        #pragma unroll
        for (int j = 0; j < 4; ++j) acc[i][j] = f32x4_t{0.f,0.f,0.f,0.f};

    int scol = 8 * ((lane & 7) ^ ((lane >> 3) & 7));
    const fp16* ga = A + (size_t)(m0 + wid*32 + (lane >> 3)) * K + scol;
    const fp16* gb = W + (size_t)(n0 + wid*32 + (lane >> 3)) * K + scol;
    int lbase = wid * 2048;

    auto stage = [&](int buf, int k0) {
        #pragma unroll
        for (int j = 0; j < 4; ++j) {
            gld16(ga + k0 + (size_t)j*8*K, &Asb[buf][lbase + j*512]);
            gld16(gb + k0 + (size_t)j*8*K, &Bsb[buf][lbase + j*512]);
        }
    };

    int nt = K >> 6;
    stage(0, 0);
    asm volatile("s_waitcnt vmcnt(0)" ::: "memory");
    __builtin_amdgcn_s_barrier();

    for (int t = 0; t < nt; ++t) {
        int cur = t & 1;
        if (t + 1 < nt) stage(cur ^ 1, (t + 1) << 6);
        #pragma unroll
        for (int kk = 0; kk < 2; ++kk) {
            f16x8_t av[4], bv[4];
            #pragma unroll
            for (int mi = 0; mi < 4; ++mi) {
                int ar = wm*64 + mi*16 + l15;
                av[mi] = *(const f16x8_t*)&Asb[cur][ar*64 + ((kk*32 + lg*8) ^ ((ar & 7) << 3))];
            }
            #pragma unroll
            for (int ni = 0; ni < 4; ++ni) {
                int br = wn*64 + ni*16 + l15;
                bv[ni] = *(const f16x8_t*)&Bsb[cur][br*64 + ((kk*32 + lg*8) ^ ((br & 7) << 3))];
            }
            __builtin_amdgcn_s_setprio(1);
            #pragma unroll
            for (int mi = 0; mi < 4; ++mi)
                #pragma unroll
                for (int ni = 0; ni < 4; ++ni)
                    acc[mi][ni] = MFMA16(av[mi], bv[ni], acc[mi][ni]);
            __builtin_amdgcn_s_setprio(0);
        }
        asm volatile("s_waitcnt vmcnt(0)" ::: "memory");
        __builtin_amdgcn_s_barrier();
    }

    if (epi == 0) {
        if (n0 < 2048) {
            // q/k region: fused rope. lane holds both rotation halves (ni and ni+2).
            float scale = (n0 >= 1024) ? 0.125f : 1.0f;
            #pragma unroll
            for (int ni = 0; ni < 2; ++ni) {
                int i = ni*16 + l15;                       // freq index 0..31
                float theta = powf(10000.f, -(float)i * (1.f/32.f));
                int n = n0 + wn*64 + ni*16 + l15;
                #pragma unroll
                for (int mi = 0; mi < 4; ++mi) {
                    int mbase = m0 + wm*64 + mi*16 + lg*4;
                    #pragma unroll
                    for (int r = 0; r < 4; ++r) {
                        int m = mbase + r;
                        float ang = (float)(m & 2047) * theta;
                        float sn, cs;
                        sincosf(ang, &sn, &cs);
                        float x1 = acc[mi][ni][r];
                        float x2 = acc[mi][ni + 2][r];
                        outB[(size_t)m * 3072 + n]      = f2h((x1*cs - x2*sn) * scale);
                        outB[(size_t)m * 3072 + n + 32] = f2h((x2*cs + x1*sn) * scale);
                    }
                }
            }
        } else {
            // V region: write transposed (bh, 64, 2048)
            #pragma unroll
            for (int mi = 0; mi < 4; ++mi) {
                int mbase = m0 + wm*64 + mi*16 + lg*4;
                #pragma unroll
                for (int ni = 0; ni < 4; ++ni) {
                    int n = n0 + wn*64 + ni*16 + l15;
                    int b = mbase >> 11;
                    int s = mbase & 2047;
                    int hd = n - 2048;
                    fp16 o4[4];
                    #pragma unroll
                    for (int r = 0; r < 4; ++r) o4[r] = f2h(acc[mi][ni][r]);
                    *(uint2*)(outB2 + (size_t)(b*1024 + hd) * 2048 + s) = *(uint2*)o4;
                }
            }
        }
    } else if (epi == 2) {
        #pragma unroll
        for (int mi = 0; mi < 4; ++mi) {
            int mbase = m0 + wm*64 + mi*16 + lg*4;
            #pragma unroll
            for (int ni = 0; ni < 4; ++ni) {
                int n = n0 + wn*64 + ni*16 + l15;
                if (n < 2816) {
                    float zb = bias[n];
                    #pragma unroll
                    for (int r = 0; r < 4; ++r) {
                        float z = acc[mi][ni][r] + zb;
                        outB[(size_t)(mbase + r) * 2816 + n] = f2h(z / (1.f + __expf(-z)));
                    }
                } else {
                    float zb = bias2[n - 2816];
                    #pragma unroll
                    for (int r = 0; r < 4; ++r)
                        outB2[(size_t)(mbase + r) * 2816 + (n - 2816)] = f2h(acc[mi][ni][r] + zb);
                }
            }
        }
    } else {
        #pragma unroll
        for (int mi = 0; mi < 4; ++mi) {
            int mbase = m0 + wm*64 + mi*16 + lg*4;
            #pragma unroll
            for (int ni = 0; ni < 4; ++ni) {
                int n = n0 + wn*64 + ni*16 + l15;
                #pragma unroll
                for (int r = 0; r < 4; ++r) {
                    int m = mbase + r;
                    float v = acc[mi][ni][r];
                    size_t idx = (size_t)m * N + n;
                    if (epi == 1) outF[idx] = resid[idx] + v;
                    else          outF[idx] = resid[idx] + v + bias[n];
                }
            }
        }
    }
}

// ---------------- elementwise gate multiply ----------------
__global__ __launch_bounds__(256) void k_mul(const fp16* __restrict__ a,
                                             const fp16* __restrict__ b,
                                             fp16* __restrict__ o, int n) {
    int i = (blockIdx.x * 256 + threadIdx.x) * 8;
    if (i >= n) return;
    uint4 va = *(const uint4*)(a + i);
    uint4 vb = *(const uint4*)(b + i);
    fp16* pa = (fp16*)&va; fp16* pb = (fp16*)&vb;
    fp16 ov[8];
    #pragma unroll
    for (int j = 0; j < 8; ++j) ov[j] = f2h(h2f(pa[j]) * h2f(pb[j]));
    *(uint4*)(o + i) = *(uint4*)ov;
}

extern "C" void kernel_launch(void* const* d_in, const int* in_sizes, int n_in,
                              void* d_out, int out_size, void* d_ws, size_t ws_size,
                              hipStream_t stream) {
    const float* x      = (const float*)d_in[0];
    const int*   mask   = (const int*)  d_in[1];
    const float* w_q    = (const float*)d_in[2];
    const float* w_k    = (const float*)d_in[3];
    const float* w_v    = (const float*)d_in[4];
    const float* w_o    = (const float*)d_in[5];
    const float* w_gate = (const float*)d_in[6];
    const float* b_gate = (const float*)d_in[7];
    const float* w_up   = (const float*)d_in[8];
    const float* b_up   = (const float*)d_in[9];
    const float* w_down = (const float*)d_in[10];
    const float* b_down = (const float*)d_in[11];
    const float* ln1g   = (const float*)d_in[12];
    const float* ln1b   = (const float*)d_in[13];
    const float* ln2g   = (const float*)d_in[14];
    const float* ln2b   = (const float*)d_in[15];
    float* out = (float*)d_out;

    char* ws = (char*)d_ws;
    size_t off = 0;
    auto walloc = [&](size_t bytes) -> void* {
        void* p = ws + off;
        off += (bytes + 255) & ~(size_t)255;
        return p;
    };
    fp16*  wqkv = (fp16*)walloc((size_t)3072*1024*2);
    fp16*  wo   = (fp16*)walloc((size_t)1024*1024*2);
    fp16*  wgu  = (fp16*)walloc((size_t)5632*1024*2);
    fp16*  wd   = (fp16*)walloc((size_t)1024*2816*2);
    fp16*  xn   = (fp16*)walloc((size_t)4096*1024*2);
    fp16*  qkv  = (fp16*)walloc((size_t)4096*3072*2);
    fp16*  vtb  = (fp16*)walloc((size_t)32*64*2048*2);
    fp16*  mh   = (fp16*)walloc((size_t)4096*1024*2);
    fp16*  sg   = (fp16*)walloc((size_t)4096*2816*2);
    fp16*  ub   = (fp16*)walloc((size_t)4096*2816*2);
    float* x1   = (float*)qkv;

    dim3 blk(256);
    k_convert_all<<<12544, blk, 0, stream>>>(w_q, w_k, w_v, w_o, w_gate, w_up, w_down,
                                             wqkv, wo, wgu, wd);

    // LN1
    k_layernorm<<<4096, blk, 0, stream>>>(x, ln1g, ln1b, xn);

    // QKV projection (N=3072) with fused rope + V-transpose epilogue
    k_gemm_bt<<<dim3(32,24), blk, 0, stream>>>(xn, wqkv, 3072, 1024, 0,
                                               nullptr, nullptr, nullptr, qkv, vtb, nullptr);

    // flash attention (reference q/k swap: A side = rope(k_proj)*0.125 at qkv+1024)
    k_attention<<<dim3(32,32), blk, 0, stream>>>(qkv + 1024, qkv, 3072, vtb, mask, mh);

    // out projection + residual -> x1 (fp32)
    k_gemm_bt<<<dim3(32,8), blk, 0, stream>>>(mh, wo, 1024, 1024, 1,
                                              nullptr, nullptr, x, nullptr, nullptr, x1);

    // LN2
    k_layernorm<<<4096, blk, 0, stream>>>(x1, ln2g, ln2b, xn);

    // gate+up combined (N=5632), 128^2 BK=64 (1408 blocks, 2/CU -> 92% tail util)
    k_gemm_bt<<<dim3(32,44), blk, 0, stream>>>(xn, wgu, 5632, 1024, 2,
                                               b_gate, b_up, nullptr, sg, ub, nullptr);

    // h = silu(gate) * up
    k_mul<<<5632, blk, 0, stream>>>(sg, ub, sg, 4096*2816);

    // down projection + bias + residual -> out (fp32)
    k_gemm_bt<<<dim3(32,8), blk, 0, stream>>>(sg, wd, 1024, 2816, 3,
                                              b_down, nullptr, x1, nullptr, nullptr, out);
}

// Round 13
// 301.402 us; speedup vs baseline: 1.3183x; 1.0610x over previous
//
#include <hip/hip_runtime.h>
#include <hip/hip_bf16.h>
#include <cstdint>
#include <cstddef>

typedef _Float16 fp16;
typedef _Float16 f16x8_t __attribute__((ext_vector_type(8)));
typedef float    f32x4_t __attribute__((ext_vector_type(4)));

#define MFMA16(a,b,c) __builtin_amdgcn_mfma_f32_16x16x32_f16((a),(b),(c),0,0,0)

static __device__ __forceinline__ float h2f(fp16 v){ return (float)v; }
static __device__ __forceinline__ fp16  f2h(float v){ return (fp16)v; }

typedef __attribute__((address_space(1))) void gvoid_t;
typedef __attribute__((address_space(3))) void lvoid_t;
static __device__ __forceinline__ void gld16(const void* g, void* l) {
    __builtin_amdgcn_global_load_lds((const gvoid_t*)g, (lvoid_t*)l, 16, 0, 0);
}

// ---------------- fp32 -> fp16 all-weights convert (one launch) ----------------
__global__ __launch_bounds__(256) void k_convert_all(
    const float* __restrict__ wq, const float* __restrict__ wk,
    const float* __restrict__ wv, const float* __restrict__ wo_,
    const float* __restrict__ wg, const float* __restrict__ wu,
    const float* __restrict__ wdn,
    fp16* __restrict__ dqkv, fp16* __restrict__ dwo,
    fp16* __restrict__ dgu, fp16* __restrict__ dwd) {
    int bid = blockIdx.x;
    const float* src; fp16* dst; int base;
    if (bid < 4096) {
        int seg = bid >> 10;
        base = (bid & 1023) * 1024;
        if      (seg == 0) { src = wq;  dst = dqkv; }
        else if (seg == 1) { src = wk;  dst = dqkv + (1 << 20); }
        else if (seg == 2) { src = wv;  dst = dqkv + (2 << 20); }
        else               { src = wo_; dst = dwo; }
    } else {
        int t = bid - 4096;
        int seg = t / 2816;
        base = (t - seg * 2816) * 1024;
        if      (seg == 0) { src = wg;  dst = dgu; }
        else if (seg == 1) { src = wu;  dst = dgu + 2816*1024; }
        else               { src = wdn; dst = dwd; }
    }
    int i = base + threadIdx.x * 4;
    float4 v = *(const float4*)(src + i);
    fp16 o[4] = { f2h(v.x), f2h(v.y), f2h(v.z), f2h(v.w) };
    *(uint2*)(dst + i) = *(uint2*)o;
}

// ---------------- LayerNorm over 1024 cols -> fp16 ----------------
__global__ __launch_bounds__(256) void k_layernorm(const float* __restrict__ x,
                                                   const float* __restrict__ g,
                                                   const float* __restrict__ b,
                                                   fp16* __restrict__ out) {
    int row = blockIdx.x;
    int tid = threadIdx.x;
    float4 v = ((const float4*)(x + (size_t)row * 1024))[tid];
    float s = v.x + v.y + v.z + v.w;
    float q = v.x*v.x + v.y*v.y + v.z*v.z + v.w*v.w;
    #pragma unroll
    for (int d = 32; d >= 1; d >>= 1) {
        s += __shfl_xor(s, d);
        q += __shfl_xor(q, d);
    }
    __shared__ float rs[4], rq[4];
    if ((tid & 63) == 0) { rs[tid >> 6] = s; rq[tid >> 6] = q; }
    __syncthreads();
    s = rs[0] + rs[1] + rs[2] + rs[3];
    q = rq[0] + rq[1] + rq[2] + rq[3];
    float mu   = s * (1.f/1024.f);
    float var  = q * (1.f/1024.f) - mu*mu;
    float rstd = rsqrtf(var + 1e-5f);
    float4 gg = ((const float4*)g)[tid];
    float4 bb = ((const float4*)b)[tid];
    fp16 o[4];
    o[0] = f2h((v.x-mu)*rstd*gg.x + bb.x);
    o[1] = f2h((v.y-mu)*rstd*gg.y + bb.y);
    o[2] = f2h((v.z-mu)*rstd*gg.z + bb.z);
    o[3] = f2h((v.w-mu)*rstd*gg.w + bb.w);
    *(uint2*)(out + (size_t)row*1024 + tid*4) = *(uint2*)o;
}

// ---------------- flash attention (gld16-staged, dbuf, XOR swizzle) ----------------
__global__ __launch_bounds__(256) void k_attention(const fp16* __restrict__ Aq,
                                                   const fp16* __restrict__ Bk,
                                                   int ld,
                                                   const fp16* __restrict__ vt,
                                                   const int* __restrict__ mask,
                                                   fp16* __restrict__ mh) {
    int bh = blockIdx.y;
    int b = bh >> 4, h = bh & 15;
    int i0 = blockIdx.x * 64;
    int tid = threadIdx.x;
    int lane = tid & 63, w = tid >> 6;
    int l15 = lane & 15, lg = lane >> 4;

    int qrow = i0 + w*16 + l15;
    const fp16* ap = Aq + (size_t)(b*2048 + qrow)*ld + h*64;
    f16x8_t af0 = *(const f16x8_t*)(ap + lg*8);        // d 0..31 slice
    f16x8_t af1 = *(const f16x8_t*)(ap + 32 + lg*8);   // d 32..63 slice

    __shared__ fp16 Kt[2][64*64];
    __shared__ fp16 Vt[2][64*64];
    __shared__ float mf[2][64];

    float m_run = -1e30f, l_run = 0.f;
    f32x4_t oacc[4];
    #pragma unroll
    for (int d2 = 0; d2 < 4; ++d2) oacc[d2] = f32x4_t{0.f,0.f,0.f,0.f};

    int scol = 8 * ((lane & 7) ^ ((lane >> 3) & 7));   // pre-swizzled source col
    const fp16* kbase = Bk + (size_t)(b*2048)*ld + h*64;
    const fp16* vbase = vt + (size_t)bh * 64 * 2048;
    const int*  mbase = mask + b*2048;

    int r0 = w*16 + (lane >> 3);
    auto stageKV = [&](int buf, int j0) {
        gld16(kbase + (size_t)(j0 + r0)*ld + scol,     &Kt[buf][w*1024]);
        gld16(kbase + (size_t)(j0 + r0 + 8)*ld + scol, &Kt[buf][w*1024 + 512]);
        gld16(vbase + (size_t)r0*2048 + j0 + scol,     &Vt[buf][w*1024]);
        gld16(vbase + (size_t)(r0+8)*2048 + j0 + scol, &Vt[buf][w*1024 + 512]);
    };

    stageKV(0, 0);
    if (tid < 64) mf[0][tid] = mbase[tid] ? 0.f : -1e9f;
    asm volatile("s_waitcnt vmcnt(0)" ::: "memory");
    __builtin_amdgcn_s_barrier();

    for (int kt = 0; kt < 32; ++kt) {
        int cur = kt & 1;
        int mv = 0;
        if (kt + 1 < 32) {
            stageKV(cur ^ 1, (kt + 1) * 64);
            if (tid < 64) mv = mbase[(kt + 1)*64 + tid];
        }

        #pragma unroll
        for (int kk = 0; kk < 2; ++kk) {   // 32-key groups
            f32x4_t st[2];
            __builtin_amdgcn_s_setprio(1);
            #pragma unroll
            for (int t2 = 0; t2 < 2; ++t2) {
                int kr = kk*32 + 8*((lane >> 2) & 3) + 4*t2 + (lane & 3);
                int cb = (kr & 7) << 3;
                f16x8_t k0 = *(const f16x8_t*)&Kt[cur][kr*64 + ((lg*8) ^ cb)];
                f16x8_t k1 = *(const f16x8_t*)&Kt[cur][kr*64 + ((32 + lg*8) ^ cb)];
                f32x4_t z = f32x4_t{0.f,0.f,0.f,0.f};
                z = MFMA16(k0, af0, z);
                z = MFMA16(k1, af1, z);
                st[t2] = z;
            }
            __builtin_amdgcn_s_setprio(0);
            float sv[8];
            float tmax = -1e30f;
            #pragma unroll
            for (int t2 = 0; t2 < 2; ++t2)
                #pragma unroll
                for (int r = 0; r < 4; ++r) {
                    float xv = st[t2][r] + mf[cur][kk*32 + 8*lg + 4*t2 + r];
                    sv[t2*4+r] = xv;
                    tmax = fmaxf(tmax, xv);
                }
            tmax = fmaxf(tmax, __shfl_xor(tmax, 16));
            tmax = fmaxf(tmax, __shfl_xor(tmax, 32));
            // exact defer-max: if no lane sees a new max, alpha == 1 identically
            bool newmax = !__all(tmax <= m_run);
            float mn = m_run;
            if (newmax) {
                mn = fmaxf(m_run, tmax);
                float alpha = __expf(m_run - mn);
                l_run *= alpha;
                #pragma unroll
                for (int d2 = 0; d2 < 4; ++d2) {
                    oacc[d2][0] *= alpha; oacc[d2][1] *= alpha;
                    oacc[d2][2] *= alpha; oacc[d2][3] *= alpha;
                }
                m_run = mn;
            }
            float p[8], ps = 0.f;
            #pragma unroll
            for (int ii = 0; ii < 8; ++ii) { p[ii] = __expf(sv[ii] - mn); ps += p[ii]; }
            ps += __shfl_xor(ps, 16);
            ps += __shfl_xor(ps, 32);
            l_run += ps;
            f16x8_t pv;
            #pragma unroll
            for (int ii = 0; ii < 8; ++ii) pv[ii] = f2h(p[ii]);
            __builtin_amdgcn_s_setprio(1);
            #pragma unroll
            for (int d2 = 0; d2 < 4; ++d2) {
                int vr = d2*16 + l15;
                f16x8_t vf = *(const f16x8_t*)&Vt[cur][vr*64 + ((kk*32 + lg*8) ^ ((vr & 7) << 3))];
                oacc[d2] = MFMA16(vf, pv, oacc[d2]);
            }
            __builtin_amdgcn_s_setprio(0);
        }

        asm volatile("s_waitcnt vmcnt(0)" ::: "memory");
        if (kt + 1 < 32 && tid < 64) mf[cur ^ 1][tid] = mv ? 0.f : -1e9f;
        __builtin_amdgcn_s_barrier();
    }
    float inv = 1.f / l_run;
    fp16* op = mh + (size_t)(b*2048 + qrow)*1024 + h*64;
    #pragma unroll
    for (int d2 = 0; d2 < 4; ++d2) {
        fp16 o4[4];
        #pragma unroll
        for (int r = 0; r < 4; ++r) o4[r] = f2h(oacc[d2][r] * inv);
        *(uint2*)(op + d2*16 + lg*4) = *(uint2*)o4;
    }
}

// ======== 128x128-tile GEMM, BK=64, 4 waves, dbuf-2, r7 schedule, 2 blocks/CU ====
// epi 0: QKV (N=3072): n<2048 -> rope fused, row-major ld 3072; n>=2048 -> V^T to outB2
// epi 1: outF = resid + acc
// epi 2: FUSED gate/up (grid.y covers 64 h-cols): B-tile = 64 gate rows + 64 up rows
//        (wid even -> gate chunk wid/2, wid odd -> up chunk wid/2);
//        epilogue outB[m*2816+n] = silu(acc_g+bias[n]) * (acc_u+bias2[n])
// epi 3: outF = resid + acc + bias[n]
__global__ __launch_bounds__(256, 2) void k_gemm_bt(const fp16* __restrict__ A,
                                                    const fp16* __restrict__ W,
                                                    int N, int K,
                                                    int epi,
                                                    const float* __restrict__ bias,
                                                    const float* __restrict__ bias2,
                                                    const float* __restrict__ resid,
                                                    fp16* __restrict__ outB,
                                                    fp16* __restrict__ outB2,
                                                    float* __restrict__ outF) {
    __shared__ fp16 Asb[2][128*64];   // 16KB per buf per operand: 64KB total
    __shared__ fp16 Bsb[2][128*64];
    int tid = threadIdx.x;
    int lane = tid & 63, wid = tid >> 6;
    int l15 = lane & 15, lg = lane >> 4;
    int m0 = blockIdx.x * 128;
    int wm = wid >> 1, wn = wid & 1;
    f32x4_t acc[4][4];
    #pragma unroll
    for (int i = 0; i < 4; ++i)
        #pragma unroll
        for (int j = 0; j < 4; ++j) acc[i][j] = f32x4_t{0.f,0.f,0.f,0.f};

    int scol = 8 * ((lane & 7) ^ ((lane >> 3) & 7));
    const fp16* ga = A + (size_t)(m0 + wid*32 + (lane >> 3)) * K + scol;
    int n0;
    const fp16* gb;
    if (epi == 2) {
        n0 = blockIdx.y * 64;
        int gbase = ((wid & 1) ? 2816 : 0) + n0 + (wid >> 1) * 32;
        gb = W + (size_t)(gbase + (lane >> 3)) * K + scol;
    } else {
        n0 = blockIdx.y * 128;
        gb = W + (size_t)(n0 + wid*32 + (lane >> 3)) * K + scol;
    }
    int lbase = wid * 2048;

    auto stage = [&](int buf, int k0) {
        #pragma unroll
        for (int j = 0; j < 4; ++j) {
            gld16(ga + k0 + (size_t)j*8*K, &Asb[buf][lbase + j*512]);
            gld16(gb + k0 + (size_t)j*8*K, &Bsb[buf][lbase + j*512]);
        }
    };

    int nt = K >> 6;
    stage(0, 0);
    asm volatile("s_waitcnt vmcnt(0)" ::: "memory");
    __builtin_amdgcn_s_barrier();

    for (int t = 0; t < nt; ++t) {
        int cur = t & 1;
        if (t + 1 < nt) stage(cur ^ 1, (t + 1) << 6);
        #pragma unroll
        for (int kk = 0; kk < 2; ++kk) {
            f16x8_t av[4], bv[4];
            #pragma unroll
            for (int mi = 0; mi < 4; ++mi) {
                int ar = wm*64 + mi*16 + l15;
                av[mi] = *(const f16x8_t*)&Asb[cur][ar*64 + ((kk*32 + lg*8) ^ ((ar & 7) << 3))];
            }
            #pragma unroll
            for (int ni = 0; ni < 4; ++ni) {
                int br = wn*64 + ni*16 + l15;
                bv[ni] = *(const f16x8_t*)&Bsb[cur][br*64 + ((kk*32 + lg*8) ^ ((br & 7) << 3))];
            }
            __builtin_amdgcn_s_setprio(1);
            #pragma unroll
            for (int mi = 0; mi < 4; ++mi)
                #pragma unroll
                for (int ni = 0; ni < 4; ++ni)
                    acc[mi][ni] = MFMA16(av[mi], bv[ni], acc[mi][ni]);
            __builtin_amdgcn_s_setprio(0);
        }
        asm volatile("s_waitcnt vmcnt(0)" ::: "memory");
        __builtin_amdgcn_s_barrier();
    }

    if (epi == 0) {
        if (n0 < 2048) {
            // q/k region: fused rope. lane holds both rotation halves (ni and ni+2).
            float scale = (n0 >= 1024) ? 0.125f : 1.0f;
            #pragma unroll
            for (int ni = 0; ni < 2; ++ni) {
                int i = ni*16 + l15;                       // freq index 0..31
                float theta = powf(10000.f, -(float)i * (1.f/32.f));
                int n = n0 + wn*64 + ni*16 + l15;
                #pragma unroll
                for (int mi = 0; mi < 4; ++mi) {
                    int mbase = m0 + wm*64 + mi*16 + lg*4;
                    #pragma unroll
                    for (int r = 0; r < 4; ++r) {
                        int m = mbase + r;
                        float ang = (float)(m & 2047) * theta;
                        float sn, cs;
                        sincosf(ang, &sn, &cs);
                        float x1 = acc[mi][ni][r];
                        float x2 = acc[mi][ni + 2][r];
                        outB[(size_t)m * 3072 + n]      = f2h((x1*cs - x2*sn) * scale);
                        outB[(size_t)m * 3072 + n + 32] = f2h((x2*cs + x1*sn) * scale);
                    }
                }
            }
        } else {
            // V region: write transposed (bh, 64, 2048)
            #pragma unroll
            for (int mi = 0; mi < 4; ++mi) {
                int mbase = m0 + wm*64 + mi*16 + lg*4;
                #pragma unroll
                for (int ni = 0; ni < 4; ++ni) {
                    int n = n0 + wn*64 + ni*16 + l15;
                    int b = mbase >> 11;
                    int s = mbase & 2047;
                    int hd = n - 2048;
                    fp16 o4[4];
                    #pragma unroll
                    for (int r = 0; r < 4; ++r) o4[r] = f2h(acc[mi][ni][r]);
                    *(uint2*)(outB2 + (size_t)(b*1024 + hd) * 2048 + s) = *(uint2*)o4;
                }
            }
        }
    } else if (epi == 2) {
        // fused gate/up: acc[mi][ni] (ni<2) = gate, acc[mi][ni+2] = up, same n
        #pragma unroll
        for (int mi = 0; mi < 4; ++mi) {
            int mbase = m0 + wm*64 + mi*16 + lg*4;
            #pragma unroll
            for (int ni = 0; ni < 2; ++ni) {
                int n = n0 + wn*32 + ni*16 + l15;
                float zbg = bias[n], zbu = bias2[n];
                #pragma unroll
                for (int r = 0; r < 4; ++r) {
                    float zg = acc[mi][ni][r] + zbg;
                    float zu = acc[mi][ni + 2][r] + zbu;
                    outB[(size_t)(mbase + r) * 2816 + n] = f2h(zg / (1.f + __expf(-zg)) * zu);
                }
            }
        }
    } else {
        #pragma unroll
        for (int mi = 0; mi < 4; ++mi) {
            int mbase = m0 + wm*64 + mi*16 + lg*4;
            #pragma unroll
            for (int ni = 0; ni < 4; ++ni) {
                int n = n0 + wn*64 + ni*16 + l15;
                #pragma unroll
                for (int r = 0; r < 4; ++r) {
                    int m = mbase + r;
                    float v = acc[mi][ni][r];
                    size_t idx = (size_t)m * N + n;
                    if (epi == 1) outF[idx] = resid[idx] + v;
                    else          outF[idx] = resid[idx] + v + bias[n];
                }
            }
        }
    }
}

extern "C" void kernel_launch(void* const* d_in, const int* in_sizes, int n_in,
                              void* d_out, int out_size, void* d_ws, size_t ws_size,
                              hipStream_t stream) {
    const float* x      = (const float*)d_in[0];
    const int*   mask   = (const int*)  d_in[1];
    const float* w_q    = (const float*)d_in[2];
    const float* w_k    = (const float*)d_in[3];
    const float* w_v    = (const float*)d_in[4];
    const float* w_o    = (const float*)d_in[5];
    const float* w_gate = (const float*)d_in[6];
    const float* b_gate = (const float*)d_in[7];
    const float* w_up   = (const float*)d_in[8];
    const float* b_up   = (const float*)d_in[9];
    const float* w_down = (const float*)d_in[10];
    const float* b_down = (const float*)d_in[11];
    const float* ln1g   = (const float*)d_in[12];
    const float* ln1b   = (const float*)d_in[13];
    const float* ln2g   = (const float*)d_in[14];
    const float* ln2b   = (const float*)d_in[15];
    float* out = (float*)d_out;

    char* ws = (char*)d_ws;
    size_t off = 0;
    auto walloc = [&](size_t bytes) -> void* {
        void* p = ws + off;
        off += (bytes + 255) & ~(size_t)255;
        return p;
    };
    fp16*  wqkv = (fp16*)walloc((size_t)3072*1024*2);
    fp16*  wo   = (fp16*)walloc((size_t)1024*1024*2);
    fp16*  wgu  = (fp16*)walloc((size_t)5632*1024*2);
    fp16*  wd   = (fp16*)walloc((size_t)1024*2816*2);
    fp16*  xn   = (fp16*)walloc((size_t)4096*1024*2);
    fp16*  qkv  = (fp16*)walloc((size_t)4096*3072*2);
    fp16*  vtb  = (fp16*)walloc((size_t)32*64*2048*2);
    fp16*  mh   = (fp16*)walloc((size_t)4096*1024*2);
    fp16*  sg   = (fp16*)walloc((size_t)4096*2816*2);
    float* x1   = (float*)qkv;

    dim3 blk(256);
    k_convert_all<<<12544, blk, 0, stream>>>(w_q, w_k, w_v, w_o, w_gate, w_up, w_down,
                                             wqkv, wo, wgu, wd);

    // LN1
    k_layernorm<<<4096, blk, 0, stream>>>(x, ln1g, ln1b, xn);

    // QKV projection (N=3072) with fused rope + V-transpose epilogue
    k_gemm_bt<<<dim3(32,24), blk, 0, stream>>>(xn, wqkv, 3072, 1024, 0,
                                               nullptr, nullptr, nullptr, qkv, vtb, nullptr);

    // flash attention (reference q/k swap: A side = rope(k_proj)*0.125 at qkv+1024)
    k_attention<<<dim3(32,32), blk, 0, stream>>>(qkv + 1024, qkv, 3072, vtb, mask, mh);

    // out projection + residual -> x1 (fp32)
    k_gemm_bt<<<dim3(32,8), blk, 0, stream>>>(mh, wo, 1024, 1024, 1,
                                              nullptr, nullptr, x, nullptr, nullptr, x1);

    // LN2
    k_layernorm<<<4096, blk, 0, stream>>>(x1, ln2g, ln2b, xn);

    // FUSED gate+up+silu+mul: grid.y = 2816/64 = 44, h written directly to sg
    k_gemm_bt<<<dim3(32,44), blk, 0, stream>>>(xn, wgu, 2816, 1024, 2,
                                               b_gate, b_up, nullptr, sg, nullptr, nullptr);

    // down projection + bias + residual -> out (fp32)
    k_gemm_bt<<<dim3(32,8), blk, 0, stream>>>(sg, wd, 1024, 2816, 3,
                                              b_down, nullptr, x1, nullptr, nullptr, out);
}